// Round 14
// baseline (51.608 us; speedup 1.0000x reference)
//
#include <hip/hip_runtime.h>

#define DPROJ 1024

typedef short  bf16x8 __attribute__((ext_vector_type(8)));
typedef float  f32x4  __attribute__((ext_vector_type(4)));

__device__ __forceinline__ unsigned short f2bf(float f) {
  unsigned u = __builtin_bit_cast(unsigned, f);
  u += 0x7FFFu + ((u >> 16) & 1u);          // round-to-nearest-even
  return (unsigned short)(u >> 16);
}

__device__ __forceinline__ bf16x8 pack8(float4 lo, float4 hi) {
  bf16x8 r;
  r[0] = (short)f2bf(lo.x); r[1] = (short)f2bf(lo.y);
  r[2] = (short)f2bf(lo.z); r[3] = (short)f2bf(lo.w);
  r[4] = (short)f2bf(hi.x); r[5] = (short)f2bf(hi.y);
  r[6] = (short)f2bf(hi.z); r[7] = (short)f2bf(hi.w);
  return r;
}

__device__ __forceinline__ int bucket_of(int v) {
  return (v >= 200000) ? 3 : (v >= 40000) ? 2 : (v >= 20000) ? 1 : 0;
}

// ---------------------------------------------------------------------------
// Kernel 1: convert the 4 proj matrices fp32 -> bf16 into ws, concatenated.
// Elem offsets: p0 @0 (1048576), p1 @1048576 (262144), p2 @1310720 (65536),
// p3 @1376256 (16384); total 1392640. 2.72 MB -> fits every XCD L2.
// (Verified correct in round 10.)
// ---------------------------------------------------------------------------
__global__ __launch_bounds__(256) void convert_proj(const float* __restrict__ p0,
                                                    const float* __restrict__ p1,
                                                    const float* __restrict__ p2,
                                                    const float* __restrict__ p3,
                                                    unsigned short* __restrict__ pb) {
  size_t base = ((size_t)blockIdx.x * 256 + threadIdx.x) * 8;
  if (base >= 1392640u) return;
  const float* src;
  if      (base < 1048576u) src = p0 + base;
  else if (base < 1310720u) src = p1 + (base - 1048576u);
  else if (base < 1376256u) src = p2 + (base - 1310720u);
  else                      src = p3 + (base - 1376256u);
  float4 lo = reinterpret_cast<const float4*>(src)[0];
  float4 hi = reinterpret_cast<const float4*>(src)[1];
  *reinterpret_cast<bf16x8*>(pb + base) = pack8(lo, hi);
}

// ---------------------------------------------------------------------------
// Bucket sub-GEMM over sorted row range [s,e) of the block's 256 tokens.
// A staged (gathered, fp32->bf16) only for rows [s&~15, ceil16(e)); rows
// outside [s,e) zeroed. B from pre-converted bf16 table. MFMA fragments
// fully outside [s,e) are skipped (wave-uniform). LDS rows 128 B with XOR
// swizzle byte ^= (row&7)<<4 (G4).
// ---------------------------------------------------------------------------
template <int D>
__device__ __forceinline__ void process_bucket(
    const float* __restrict__ emb, const unsigned short* __restrict__ pbi,
    int c0, int s, int e, const int* __restrict__ s_idx,
    char* __restrict__ Ab, char* __restrict__ Bb,
    f32x4 (&acc)[4][4], int tid, int wr, int wc, int lr, int t16) {
  if (s == e) return;                       // block-uniform -> safe
  constexpr int NCH = (D + 63) / 64;        // 16, 4, 1, 1
  constexpr int KR  = (D < 64) ? D : 64;    // real k per chunk
  constexpr int S   = (KR >= 64) ? 2 : 1;   // K=32 MFMA steps per chunk
  const int lo16 = s & ~15;
  const int hi16 = (e + 15) & ~15;
  const int ngr  = (hi16 - lo16) * 8;       // 8-elem groups to stage for A

  for (int ch = 0; ch < NCH; ++ch) {
    const int k0 = ch * 64;
    // ---- stage A (active rows only; edges zeroed)
    for (int g = tid; g < ngr; g += 512) {
      int row = lo16 + (g >> 3);
      int kk  = (g & 7) * 8;
      bf16x8 o = {0, 0, 0, 0, 0, 0, 0, 0};
      if (row >= s && row < e && kk < KR) {
        const float* p = emb + (size_t)s_idx[row] * D + k0 + kk;
        float4 lo = *reinterpret_cast<const float4*>(p);
        float4 hi = *reinterpret_cast<const float4*>(p + 4);
        o = pack8(lo, hi);
      }
      *reinterpret_cast<bf16x8*>(Ab + row * 128 + ((kk * 2) ^ ((row & 7) << 4))) = o;
    }
    // ---- stage B: 128 cols x 64 k (zeros beyond KR), 1024 groups
#pragma unroll
    for (int i = 0; i < 2; ++i) {
      int g = tid + i * 512;
      int col = g >> 3, kk = (g & 7) * 8;
      bf16x8 o = {0, 0, 0, 0, 0, 0, 0, 0};
      if (kk < KR)
        o = *reinterpret_cast<const bf16x8*>(pbi + (size_t)(c0 + col) * D + k0 + kk);
      *reinterpret_cast<bf16x8*>(Bb + col * 128 + ((kk * 2) ^ ((col & 7) << 4))) = o;
    }
    __syncthreads();

    // ---- MFMA with fragment skipping
#pragma unroll
    for (int st = 0; st < S; ++st) {
      bf16x8 bfr[4];
#pragma unroll
      for (int fj = 0; fj < 4; ++fj) {
        int col = wc * 64 + fj * 16 + lr;
        bfr[fj] = *reinterpret_cast<const bf16x8*>(
            Bb + col * 128 + ((st * 64 + t16 * 16) ^ ((col & 7) << 4)));
      }
#pragma unroll
      for (int fi = 0; fi < 4; ++fi) {
        int rb = wr * 64 + fi * 16;         // frag rows [rb, rb+16)
        if (rb + 16 > s && rb < e) {        // intersects active range (uniform)
          int row = rb + lr;
          bf16x8 a = *reinterpret_cast<const bf16x8*>(
              Ab + row * 128 + ((st * 64 + t16 * 16) ^ ((row & 7) << 4)));
#pragma unroll
          for (int fj = 0; fj < 4; ++fj)
            acc[fi][fj] = __builtin_amdgcn_mfma_f32_16x16x32_bf16(a, bfr[fj], acc[fi][fj], 0, 0, 0);
        }
      }
    }
    __syncthreads();
  }
}

// ---------------------------------------------------------------------------
// Kernel 2: FUSED token-ordered GEMM. Block = 256 consecutive tokens x 128
// cols; 8 waves (4x2: 64 rows x 64 cols each). In-block stable counting sort
// groups tokens by bucket -> contiguous row ranges -> MFMA frag skipping
// keeps total MFMA ~1.2x useful. Epilogue un-permutes -> stores sweep the
// output strictly in token order (block = 1 MB contiguous span).
// No lists / counts / atomics anywhere. C/D frag: col = lane&15,
// row = (lane>>4)*4 + reg (HW-verified rounds 1-13).
// ---------------------------------------------------------------------------
__global__ __launch_bounds__(512) void fused_gemm(
    const int* __restrict__ inp,
    const float* __restrict__ e0, const float* __restrict__ e1,
    const float* __restrict__ e2, const float* __restrict__ e3,
    const unsigned short* __restrict__ pb,
    float* __restrict__ out, int n) {
  __shared__ char Ab[32768];                // A: 256 rows x 128 B (bf16)
  __shared__ char Bb[16384];                // B: 128 cols x 128 B (bf16)
  __shared__ int  s_orig[256];              // sorted pos -> original row
  __shared__ int  s_idx[256];               // sorted pos -> in-bucket idx
  __shared__ int  s_cnt[4][4];              // [wave<4][bucket]
  __shared__ int  s_woff[4][4];             // wave write base per bucket
  __shared__ int  s_base[5];                // bucket boundaries in sorted order

  const int tid  = threadIdx.x;
  const int t0   = (blockIdx.x >> 3) * 256; // token base
  const int c0   = (blockIdx.x & 7) * 128;  // col base
  const int lane = tid & 63, w = tid >> 6;
  const int wr   = w >> 1, wc = w & 1;      // 4x2 wave grid
  const int lr   = lane & 15, t16 = lane >> 4;

  // ---- load 256 tokens, stable counting sort by bucket (waves 0-3)
  int v = 0, b = 0, rank = 0;
  if (tid < 256) {
    v = (t0 + tid < n) ? inp[t0 + tid] : 0; // tail tokens -> bucket 0, idx 0
    b = bucket_of(v);
    if (t0 + tid >= n) { v = 0; b = 0; }
#pragma unroll
    for (int i = 0; i < 4; ++i) {
      unsigned long long m = __ballot(b == i);
      if (lane == 0) s_cnt[w][i] = __popcll(m);
      if (b == i) rank = __popcll(m & ((1ull << lane) - 1ull));
    }
  }
  __syncthreads();
  if (tid == 0) {
    int base = 0;
#pragma unroll
    for (int i = 0; i < 4; ++i) {
      s_base[i] = base;
#pragma unroll
      for (int ww = 0; ww < 4; ++ww) { s_woff[ww][i] = base; base += s_cnt[ww][i]; }
    }
    s_base[4] = base;                       // == 256
  }
  __syncthreads();
  if (tid < 256) {
    int lo = (b == 3) ? 200000 : (b == 2) ? 40000 : (b == 1) ? 20000 : 0;
    int pos = s_woff[w][b] + rank;
    s_orig[pos] = tid;
    s_idx[pos]  = v - lo;
  }
  __syncthreads();

  const int b0s = s_base[0], b1s = s_base[1], b2s = s_base[2],
            b3s = s_base[3], b4s = s_base[4];

  f32x4 acc[4][4];
#pragma unroll
  for (int fi = 0; fi < 4; ++fi)
#pragma unroll
    for (int fj = 0; fj < 4; ++fj) acc[fi][fj] = (f32x4){0.f, 0.f, 0.f, 0.f};

  process_bucket<1024>(e0, pb,           c0, b0s, b1s, s_idx, Ab, Bb, acc, tid, wr, wc, lr, t16);
  process_bucket< 256>(e1, pb + 1048576, c0, b1s, b2s, s_idx, Ab, Bb, acc, tid, wr, wc, lr, t16);
  process_bucket<  64>(e2, pb + 1310720, c0, b2s, b3s, s_idx, Ab, Bb, acc, tid, wr, wc, lr, t16);
  process_bucket<  16>(e3, pb + 1376256, c0, b3s, b4s, s_idx, Ab, Bb, acc, tid, wr, wc, lr, t16);

  // ---- epilogue: per-wave transpose (region w*4352 in Ab/Bb, disjoint,
  // all waves past the last chunk barrier), un-permute, token-ordered stores.
  float* T = reinterpret_cast<float*>(Ab + w * 4352);  // 16 rows x stride 68
#pragma unroll
  for (int fi = 0; fi < 4; ++fi) {
#pragma unroll
    for (int fj = 0; fj < 4; ++fj)
#pragma unroll
      for (int reg = 0; reg < 4; ++reg)
        T[(t16 * 4 + reg) * 68 + fj * 16 + lr] = acc[fi][fj][reg];
    // same-wave ds_write->ds_read ordering via compiler lgkmcnt
#pragma unroll
    for (int rr = 0; rr < 4; ++rr) {
      int sr   = wr * 64 + fi * 16 + rr * 4 + t16;   // sorted row
      int orow = s_orig[sr];                          // original row in tile
      if (t0 + orow < n) {
        float4 vv = *reinterpret_cast<const float4*>(&T[(rr * 4 + t16) * 68 + lr * 4]);
        *reinterpret_cast<float4*>(out + (size_t)(t0 + orow) * DPROJ +
                                   c0 + wc * 64 + lr * 4) = vv;
      }
    }
  }
}

// ---------------------------------------------------------------------------
// Input order (setup_inputs dict order, verified rounds 1-13):
// inp, emb0, proj0, emb1, proj1, emb2, proj2, emb3, proj3.
// ws layout: [@0: bf16 proj tables, 2.72 MB].
// ---------------------------------------------------------------------------
extern "C" void kernel_launch(void* const* d_in, const int* in_sizes, int n_in,
                              void* d_out, int out_size, void* d_ws, size_t ws_size,
                              hipStream_t stream) {
  const int*   inp   = (const int*)d_in[0];
  const float* emb0  = (const float*)d_in[1];
  const float* proj0 = (const float*)d_in[2];
  const float* emb1  = (const float*)d_in[3];
  const float* proj1 = (const float*)d_in[4];
  const float* emb2  = (const float*)d_in[5];
  const float* proj2 = (const float*)d_in[6];
  const float* emb3  = (const float*)d_in[7];
  const float* proj3 = (const float*)d_in[8];
  float* out = (float*)d_out;
  const int n = in_sizes[0];  // 16384 tokens

  unsigned short* pb = (unsigned short*)d_ws;

  convert_proj<<<dim3(680), dim3(256), 0, stream>>>(proj0, proj1, proj2, proj3, pb);

  int tiles = (n + 255) / 256;              // 64
  fused_gemm<<<dim3(tiles * 8), dim3(512), 0, stream>>>(inp, emb0, emb1, emb2, emb3,
                                                        pb, out, n);
}

// Round 15
// 46.030 us; speedup vs baseline: 1.1212x; 1.1212x over previous
//
#include <hip/hip_runtime.h>

#define DPROJ 1024

typedef short  bf16x8 __attribute__((ext_vector_type(8)));
typedef float  f32x4  __attribute__((ext_vector_type(4)));

__device__ __forceinline__ unsigned short f2bf(float f) {
  unsigned u = __builtin_bit_cast(unsigned, f);
  u += 0x7FFFu + ((u >> 16) & 1u);          // round-to-nearest-even
  return (unsigned short)(u >> 16);
}

__device__ __forceinline__ bf16x8 pack8(float4 lo, float4 hi) {
  bf16x8 r;
  r[0] = (short)f2bf(lo.x); r[1] = (short)f2bf(lo.y);
  r[2] = (short)f2bf(lo.z); r[3] = (short)f2bf(lo.w);
  r[4] = (short)f2bf(hi.x); r[5] = (short)f2bf(hi.y);
  r[6] = (short)f2bf(hi.z); r[7] = (short)f2bf(hi.w);
  return r;
}

__device__ __forceinline__ int bucket_of(int v) {
  return (v >= 200000) ? 3 : (v >= 40000) ? 2 : (v >= 20000) ? 1 : 0;
}

// ---------------------------------------------------------------------------
// Kernel 1: fused proj fp32->bf16 conversion (680 blocks) + per-block bucket
// counts (first nb blocks). pb elem offsets: p0 @0, p1 @1048576, p2 @1310720,
// p3 @1376256; total 1392640 (2.72 MB, fits every XCD L2).
// ---------------------------------------------------------------------------
__global__ __launch_bounds__(256) void convert_count(
    const float* __restrict__ p0, const float* __restrict__ p1,
    const float* __restrict__ p2, const float* __restrict__ p3,
    unsigned short* __restrict__ pb,
    const int* __restrict__ inp, int n, int nb, int* __restrict__ blkcnt) {
  size_t base = ((size_t)blockIdx.x * 256 + threadIdx.x) * 8;
  if (base < 1392640u) {
    const float* src;
    if      (base < 1048576u) src = p0 + base;
    else if (base < 1310720u) src = p1 + (base - 1048576u);
    else if (base < 1376256u) src = p2 + (base - 1310720u);
    else                      src = p3 + (base - 1376256u);
    float4 lo = reinterpret_cast<const float4*>(src)[0];
    float4 hi = reinterpret_cast<const float4*>(src)[1];
    *reinterpret_cast<bf16x8*>(pb + base) = pack8(lo, hi);
  }
  if (blockIdx.x < (unsigned)nb) {
    int t = blockIdx.x * 256 + threadIdx.x;
    int lane = threadIdx.x & 63, w = threadIdx.x >> 6;
    int v = (t < n) ? inp[t] : -1;
    int b = (v < 0) ? -1 : bucket_of(v);
    __shared__ int cnt[4][4];
#pragma unroll
    for (int i = 0; i < 4; ++i) {
      unsigned long long m = __ballot(b == i);
      if (lane == 0) cnt[w][i] = __popcll(m);
    }
    __syncthreads();
    if (threadIdx.x < 4) {
      int s = cnt[0][threadIdx.x] + cnt[1][threadIdx.x] +
              cnt[2][threadIdx.x] + cnt[3][threadIdx.x];
      blkcnt[blockIdx.x * 4 + threadIdx.x] = s;
    }
  }
}

// ---------------------------------------------------------------------------
// Kernel 2: scatter with inline scan (r13, verified). Token-ascending lists.
// Entry packs (in-bucket row << 14) | token_id  (n = 16384 = 2^14).
// ---------------------------------------------------------------------------
__global__ __launch_bounds__(256) void scatter_kernel(const int* __restrict__ inp, int n,
                                                      const int* __restrict__ blkcnt, int nb,
                                                      unsigned* __restrict__ lists,
                                                      int* __restrict__ counts) {
  int t = blockIdx.x * 256 + threadIdx.x;
  int lane = threadIdx.x & 63, w = threadIdx.x >> 6;
  __shared__ int cnt[4][4];
  __shared__ int off_s[4];
  {
    int sv = (lane < nb) ? blkcnt[lane * 4 + w] : 0;
    int x = sv;
#pragma unroll
    for (int d = 1; d < 64; d <<= 1) {
      int y = __shfl_up(x, d);
      if (lane >= d) x += y;
    }
    int myoff = __shfl(x - sv, blockIdx.x);
    if (lane == 0) off_s[w] = myoff;
    if (blockIdx.x == 0 && lane == 63) counts[w] = x;
  }
  int v = (t < n) ? inp[t] : -1;
  int b = (v < 0) ? -1 : bucket_of(v);
  int lo = (b == 3) ? 200000 : (b == 2) ? 40000 : (b == 1) ? 20000 : 0;
  int myrank = 0;
#pragma unroll
  for (int i = 0; i < 4; ++i) {
    unsigned long long m = __ballot(b == i);
    if (lane == 0) cnt[w][i] = __popcll(m);
    if (b == i) myrank = __popcll(m & ((1ull << lane) - 1ull));
  }
  __syncthreads();
  if (b >= 0) {
    int prefix = 0;
    for (int w2 = 0; w2 < w; ++w2) prefix += cnt[w2][b];
    int pos = off_s[b] + prefix + myrank;
    lists[(size_t)b * n + pos] = ((unsigned)(v - lo) << 14) | (unsigned)t;
  }
}

// ---------------------------------------------------------------------------
// Heavy path: CHB K-chunks starting at chunk ch0. Prefetch DISTANCE 2 (two
// static register sets, loop fully unrolled so set indices are compile-time).
// A from fp32 emb (gathered, converted in staging); B from pre-converted bf16
// table (no conversion VALU, half the bytes). LDS XOR swizzle (G4).
// PARTIAL: store [64][128] fp32 tile to dst (split-K ws); else scatter to out.
// ---------------------------------------------------------------------------
template <int D, int CHB, bool PARTIAL>
__device__ __forceinline__ void gemm_heavy(const float* __restrict__ emb,
                                           const unsigned short* __restrict__ pbD,
                                           const unsigned* __restrict__ list,
                                           int cnt, int r0, int c0, int ch0,
                                           float* __restrict__ dst, char* smem) {
  const int tid  = threadIdx.x;
  const int lane = tid & 63;
  const int w    = tid >> 6;
  const int wr   = w >> 1, wc = w & 1;     // 2x2 wave grid: 32 rows x 64 cols
  const int lr   = lane & 15, t16 = lane >> 4;

  char* Ab = smem;                          // A: 64 rows x 128 B  =  8 KB
  char* Bb = smem + 8192;                   // B: 128 cols x 128 B = 16 KB
  unsigned* toks = (unsigned*)(smem + 24576);

  if (tid < 64) {
    int p = r0 + tid;
    toks[tid] = (p < cnt) ? list[p] : 0u;   // pads -> row 0 (stores suppressed)
  }
  __syncthreads();

  // staging geometry: A 512 groups (2/thread), B 1024 groups (4/thread)
  int rowA[2], kkA[2], colB[4], kkB[4];
#pragma unroll
  for (int i = 0; i < 2; ++i) {
    int g = tid + i * 256;
    rowA[i] = g >> 3; kkA[i] = (g & 7) * 8;
  }
#pragma unroll
  for (int i = 0; i < 4; ++i) {
    int g = tid + i * 256;
    colB[i] = g >> 3; kkB[i] = (g & 7) * 8;
  }
  const float* abase[2];
#pragma unroll
  for (int i = 0; i < 2; ++i)
    abase[i] = emb + (size_t)(toks[rowA[i]] >> 14) * D + kkA[i];
  const unsigned short* bbase[4];
#pragma unroll
  for (int i = 0; i < 4; ++i)
    bbase[i] = pbD + (size_t)(c0 + colB[i]) * D + kkB[i];

  float4  arg[2][2][2];                     // [set][group][lo/hi]
  bf16x8  brg[2][4];                        // [set][group]

#define LOAD_SET(S_, K0_)                                                   \
  {                                                                         \
    _Pragma("unroll")                                                       \
    for (int i = 0; i < 2; ++i) {                                           \
      arg[S_][i][0] = *reinterpret_cast<const float4*>(abase[i] + (K0_));   \
      arg[S_][i][1] = *reinterpret_cast<const float4*>(abase[i] + (K0_) + 4);\
    }                                                                       \
    _Pragma("unroll")                                                       \
    for (int i = 0; i < 4; ++i)                                             \
      brg[S_][i] = *reinterpret_cast<const bf16x8*>(bbase[i] + (K0_));      \
  }

  LOAD_SET(0, ch0 * 64)
  if (CHB > 1) LOAD_SET(1, (ch0 + 1) * 64)

  f32x4 acc[2][4];
#pragma unroll
  for (int fi = 0; fi < 2; ++fi)
#pragma unroll
    for (int fj = 0; fj < 4; ++fj) acc[fi][fj] = (f32x4){0.f, 0.f, 0.f, 0.f};

#pragma unroll
  for (int ch = 0; ch < CHB; ++ch) {
    const int cur = ch & 1;                 // compile-time after unroll
    // ---- commit set[cur] -> LDS (vmcnt waits only for that set's loads)
#pragma unroll
    for (int i = 0; i < 2; ++i) {
      bf16x8 o = pack8(arg[cur][i][0], arg[cur][i][1]);
      *reinterpret_cast<bf16x8*>(Ab + rowA[i] * 128 +
                                 ((kkA[i] * 2) ^ ((rowA[i] & 7) << 4))) = o;
    }
#pragma unroll
    for (int i = 0; i < 4; ++i)
      *reinterpret_cast<bf16x8*>(Bb + colB[i] * 128 +
                                 ((kkB[i] * 2) ^ ((colB[i] & 7) << 4))) = brg[cur][i];
    __syncthreads();

    // ---- refill set[cur] for chunk ch+2 (window ~1.5 chunks >> HBM latency)
    if (ch + 2 < CHB) LOAD_SET(cur, (ch0 + ch + 2) * 64)

    // ---- compute chunk ch
#pragma unroll
    for (int s = 0; s < 2; ++s) {
      bf16x8 a[2], b[4];
#pragma unroll
      for (int fi = 0; fi < 2; ++fi) {
        int row = wr * 32 + fi * 16 + lr;
        a[fi] = *reinterpret_cast<const bf16x8*>(
            Ab + row * 128 + ((s * 64 + t16 * 16) ^ ((row & 7) << 4)));
      }
#pragma unroll
      for (int fj = 0; fj < 4; ++fj) {
        int col = wc * 64 + fj * 16 + lr;
        b[fj] = *reinterpret_cast<const bf16x8*>(
            Bb + col * 128 + ((s * 64 + t16 * 16) ^ ((col & 7) << 4)));
      }
#pragma unroll
      for (int fi = 0; fi < 2; ++fi)
#pragma unroll
        for (int fj = 0; fj < 4; ++fj)
          acc[fi][fj] = __builtin_amdgcn_mfma_f32_16x16x32_bf16(a[fi], b[fj], acc[fi][fj], 0, 0, 0);
    }
    __syncthreads();
  }
#undef LOAD_SET

  // ---- epilogue: per-wave LDS transpose then float4 stores.
  float* T = reinterpret_cast<float*>(smem + w * 4352);  // 16 rows x stride 68
#pragma unroll
  for (int fi = 0; fi < 2; ++fi) {
#pragma unroll
    for (int fj = 0; fj < 4; ++fj)
#pragma unroll
      for (int reg = 0; reg < 4; ++reg)
        T[(t16 * 4 + reg) * 68 + fj * 16 + lr] = acc[fi][fj][reg];
#pragma unroll
    for (int rr = 0; rr < 4; ++rr) {
      int p = wr * 32 + fi * 16 + rr * 4 + t16;
      if (r0 + p < cnt) {
        float4 v = *reinterpret_cast<const float4*>(&T[(rr * 4 + t16) * 68 + lr * 4]);
        if (PARTIAL)
          *reinterpret_cast<float4*>(dst + (size_t)p * 128 + wc * 64 + lr * 4) = v;
        else
          *reinterpret_cast<float4*>(dst + (size_t)(toks[p] & 16383u) * DPROJ +
                                     c0 + wc * 64 + lr * 4) = v;
      }
    }
  }
}

// ---------------------------------------------------------------------------
// Light path (D = 64 or 16): register-direct fragments; B from bf16 table.
// ---------------------------------------------------------------------------
template <int D>
__device__ __forceinline__ void gemm_light(const float* __restrict__ emb,
                                           const unsigned short* __restrict__ pbD,
                                           const unsigned* __restrict__ list,
                                           int cnt, int r0, int c0,
                                           float* __restrict__ out, char* smem) {
  constexpr int S = (D == 64) ? 2 : 1;
  const int tid  = threadIdx.x;
  const int lane = tid & 63;
  const int w    = tid >> 6;
  const int wr   = w >> 1, wc = w & 1;
  const int lr   = lane & 15, t16 = lane >> 4;

  unsigned* toks = (unsigned*)smem;
  if (tid < 64) {
    int p = r0 + tid;
    toks[tid] = (p < cnt) ? list[p] : 0u;
  }
  __syncthreads();

  bf16x8 a[2][S], b[4][S];
#pragma unroll
  for (int fi = 0; fi < 2; ++fi) {
    const float* eb = emb + (size_t)(toks[wr * 32 + fi * 16 + lr] >> 14) * D;
#pragma unroll
    for (int s = 0; s < S; ++s) {
      float4 lo = make_float4(0.f, 0.f, 0.f, 0.f), hi = lo;
      if (D == 64 || t16 < 2) {
        lo = *reinterpret_cast<const float4*>(eb + s * 32 + t16 * 8);
        hi = *reinterpret_cast<const float4*>(eb + s * 32 + t16 * 8 + 4);
      }
      a[fi][s] = pack8(lo, hi);
    }
  }
#pragma unroll
  for (int fj = 0; fj < 4; ++fj) {
    const unsigned short* pbc = pbD + (size_t)(c0 + wc * 64 + fj * 16 + lr) * D;
#pragma unroll
    for (int s = 0; s < S; ++s) {
      bf16x8 z = {0, 0, 0, 0, 0, 0, 0, 0};
      if (D == 64 || t16 < 2)
        z = *reinterpret_cast<const bf16x8*>(pbc + s * 32 + t16 * 8);
      b[fj][s] = z;
    }
  }

  f32x4 acc[2][4];
#pragma unroll
  for (int fi = 0; fi < 2; ++fi)
#pragma unroll
    for (int fj = 0; fj < 4; ++fj) acc[fi][fj] = (f32x4){0.f, 0.f, 0.f, 0.f};
#pragma unroll
  for (int s = 0; s < S; ++s)
#pragma unroll
    for (int fi = 0; fi < 2; ++fi)
#pragma unroll
      for (int fj = 0; fj < 4; ++fj)
        acc[fi][fj] = __builtin_amdgcn_mfma_f32_16x16x32_bf16(a[fi][s], b[fj][s], acc[fi][fj], 0, 0, 0);

  float* T = reinterpret_cast<float*>(smem + 256) + w * 1088;
#pragma unroll
  for (int fi = 0; fi < 2; ++fi) {
#pragma unroll
    for (int fj = 0; fj < 4; ++fj)
#pragma unroll
      for (int reg = 0; reg < 4; ++reg)
        T[(t16 * 4 + reg) * 68 + fj * 16 + lr] = acc[fi][fj][reg];
#pragma unroll
    for (int rr = 0; rr < 4; ++rr) {
      int p = wr * 32 + fi * 16 + rr * 4 + t16;
      if (r0 + p < cnt) {
        float4 v = *reinterpret_cast<const float4*>(&T[(rr * 4 + t16) * 68 + lr * 4]);
        *reinterpret_cast<float4*>(out + (size_t)(toks[p] & 16383u) * DPROJ +
                                   c0 + wc * 64 + lr * 4) = v;
      }
    }
  }
}

// ---------------------------------------------------------------------------
// Dispatcher. Segments: [b0 split-K: bx = kz*(sk*8) + tile*8 + slice, so all
// 4 kz of (tile,slice) land on XCD = slice -> partials stay in one L2]
// [b0 overflow full-K][b1 4-chunk][b2][b3]. Heavy first.
// ---------------------------------------------------------------------------
__global__ __launch_bounds__(256) void gemm_all(
    const float* __restrict__ e0, const float* __restrict__ e1,
    const float* __restrict__ e2, const float* __restrict__ e3,
    const unsigned short* __restrict__ pb,
    const int* __restrict__ counts, const unsigned* __restrict__ lists,
    float* __restrict__ part, float* __restrict__ out, int n, int cap) {
  extern __shared__ char smem[];
  int4 c = *reinterpret_cast<const int4*>(counts);
  int t0 = (c.x + 63) >> 6, t1 = (c.y + 63) >> 6,
      t2 = (c.z + 63) >> 6, t3 = (c.w + 63) >> 6;
  int sk = (t0 < cap) ? t0 : cap;
  int y = blockIdx.x;
  if (y < sk * 32) {                        // b0 split-K x4
    int nb0 = sk * 8;
    int kz = y / nb0, r = y % nb0;
    int tile = r >> 3, slice = r & 7;
    float* dst = part + ((size_t)(r * 4 + kz)) * 8192;
    gemm_heavy<1024, 4, true>(e0, pb, lists, c.x, tile * 64, slice * 128,
                              kz * 4, dst, smem);
    return;
  }
  y -= sk * 32;
  if (y < (t0 - sk) * 8) {                  // b0 overflow: full-K direct
    int tile = sk + (y >> 3), slice = y & 7;
    gemm_heavy<1024, 16, false>(e0, pb, lists, c.x, tile * 64, slice * 128,
                                0, out, smem);
    return;
  }
  y -= (t0 - sk) * 8;
  if (y < t1 * 8) {
    gemm_heavy<256, 4, false>(e1, pb + 1048576, lists + (size_t)n, c.y,
                              (y >> 3) * 64, (y & 7) * 128, 0, out, smem);
    return;
  }
  y -= t1 * 8;
  if (y < t2 * 8) {
    gemm_light<64>(e2, pb + 1310720, lists + (size_t)2 * n, c.z,
                   (y >> 3) * 64, (y & 7) * 128, out, smem);
    return;
  }
  y -= t2 * 8;
  if (y < t3 * 8) {
    gemm_light<16>(e3, pb + 1376256, lists + (size_t)3 * n, c.w,
                   (y >> 3) * 64, (y & 7) * 128, out, smem);
    return;
  }
}

// ---------------------------------------------------------------------------
// Kernel 4: sum 4 split-K partials per (tile,slice), scatter to out.
// Grid (8, cap): linear id = tile*8+slice -> XCD = slice = where the
// partials were written -> L2-local reads.
// ---------------------------------------------------------------------------
__global__ __launch_bounds__(256) void reduce_b0(const int* __restrict__ counts,
                                                 const unsigned* __restrict__ list0,
                                                 const float* __restrict__ part,
                                                 float* __restrict__ out, int cap) {
  int cnt = counts[0];
  int tiles = (cnt + 63) >> 6;
  if (tiles > cap) tiles = cap;
  int tile = blockIdx.y, slice = blockIdx.x;
  if (tile >= tiles) return;
  const float* base = part + ((size_t)((tile * 8 + slice) * 4)) * 8192;
  int tid = threadIdx.x;
  int r0 = tile * 64;
#pragma unroll
  for (int pass = 0; pass < 8; ++pass) {
    int row = pass * 8 + (tid >> 5);
    int p = r0 + row;
    if (p < cnt) {
      int off = row * 128 + (tid & 31) * 4;
      float4 v0 = *reinterpret_cast<const float4*>(base + off);
      float4 v1 = *reinterpret_cast<const float4*>(base + 8192 + off);
      float4 v2 = *reinterpret_cast<const float4*>(base + 16384 + off);
      float4 v3 = *reinterpret_cast<const float4*>(base + 24576 + off);
      float4 s = make_float4(v0.x + v1.x + v2.x + v3.x, v0.y + v1.y + v2.y + v3.y,
                             v0.z + v1.z + v2.z + v3.z, v0.w + v1.w + v2.w + v3.w);
      unsigned tok = list0[p] & 16383u;
      *reinterpret_cast<float4*>(out + (size_t)tok * DPROJ + slice * 128 +
                                 (tid & 31) * 4) = s;
    }
  }
}

// ---------------------------------------------------------------------------
// Input order (setup_inputs dict order, verified rounds 1-14):
// inp, emb0, proj0, emb1, proj1, emb2, proj2, emb3, proj3.
// ws bytes: [0,16) counts | [16,1040) blkcnt | [1040,263184) lists |
// [524288, 3309568) pb bf16 | [3309568, +cap MB) split-K partials.
// ---------------------------------------------------------------------------
extern "C" void kernel_launch(void* const* d_in, const int* in_sizes, int n_in,
                              void* d_out, int out_size, void* d_ws, size_t ws_size,
                              hipStream_t stream) {
  const int*   inp   = (const int*)d_in[0];
  const float* emb0  = (const float*)d_in[1];
  const float* proj0 = (const float*)d_in[2];
  const float* emb1  = (const float*)d_in[3];
  const float* proj1 = (const float*)d_in[4];
  const float* emb2  = (const float*)d_in[5];
  const float* proj2 = (const float*)d_in[6];
  const float* emb3  = (const float*)d_in[7];
  const float* proj3 = (const float*)d_in[8];
  float* out = (float*)d_out;
  const int n = in_sizes[0];  // 16384 tokens

  int*            counts = (int*)d_ws;
  int*            blkcnt = (int*)d_ws + 4;
  unsigned*       lists  = (unsigned*)d_ws + 260;
  unsigned short* pb     = (unsigned short*)((char*)d_ws + 524288);
  const size_t    PART_OFF = 3309568;                  // 524288 + 2785280
  const size_t    PER_TILE = 8u * 4u * 8192u * 4u;     // 1 MB per b0 tile
  int cap = 0;
  if (ws_size > PART_OFF) {
    size_t cc = (ws_size - PART_OFF) / PER_TILE;
    cap = (cc > 32) ? 32 : (int)cc;
  }
  float* part = (float*)((char*)d_ws + PART_OFF);

  const int nb = (n + 255) / 256;           // 64 (scan supports <= 64)
  convert_count<<<dim3(680), dim3(256), 0, stream>>>(proj0, proj1, proj2, proj3,
                                                     pb, inp, n, nb, blkcnt);
  scatter_kernel<<<dim3(nb), dim3(256), 0, stream>>>(inp, n, blkcnt, nb, lists, counts);

  // grid: worst case sk*32 (<= cap*32) + all tiles*8 (<= (n/64+3)*8)
  dim3 grid(cap * 32 + ((n + 63) / 64 + 3) * 8, 1, 1);
  size_t smem_bytes = 24576 + 64 * sizeof(unsigned);  // 24832 B
  gemm_all<<<grid, dim3(256), smem_bytes, stream>>>(emb0, emb1, emb2, emb3, pb,
                                                    counts, lists, part, out, n, cap);
  if (cap > 0)
    reduce_b0<<<dim3(8, cap), dim3(256), 0, stream>>>(counts, lists, part, out, cap);
}

// Round 16
// 35.489 us; speedup vs baseline: 1.4542x; 1.2970x over previous
//
#include <hip/hip_runtime.h>

#define DPROJ 1024

typedef short  bf16x8 __attribute__((ext_vector_type(8)));
typedef float  f32x4  __attribute__((ext_vector_type(4)));

__device__ __forceinline__ unsigned short f2bf(float f) {
  unsigned u = __builtin_bit_cast(unsigned, f);
  u += 0x7FFFu + ((u >> 16) & 1u);          // round-to-nearest-even
  return (unsigned short)(u >> 16);
}

__device__ __forceinline__ bf16x8 pack8(float4 lo, float4 hi) {
  bf16x8 r;
  r[0] = (short)f2bf(lo.x); r[1] = (short)f2bf(lo.y);
  r[2] = (short)f2bf(lo.z); r[3] = (short)f2bf(lo.w);
  r[4] = (short)f2bf(hi.x); r[5] = (short)f2bf(hi.y);
  r[6] = (short)f2bf(hi.z); r[7] = (short)f2bf(hi.w);
  return r;
}

__device__ __forceinline__ int bucket_of(int v) {
  return (v >= 200000) ? 3 : (v >= 40000) ? 2 : (v >= 20000) ? 1 : 0;
}

// ---------------------------------------------------------------------------
// Kernel 1: fused proj fp32->bf16 conversion (680 blocks) + per-block bucket
// counts (first nb blocks). pb elem offsets: p0 @0, p1 @1048576, p2 @1310720,
// p3 @1376256; total 1392640 elems (2.72 MB -> L2/L3 resident). [r15 verified]
// ---------------------------------------------------------------------------
__global__ __launch_bounds__(256) void convert_count(
    const float* __restrict__ p0, const float* __restrict__ p1,
    const float* __restrict__ p2, const float* __restrict__ p3,
    unsigned short* __restrict__ pb,
    const int* __restrict__ inp, int n, int nb, int* __restrict__ blkcnt) {
  size_t base = ((size_t)blockIdx.x * 256 + threadIdx.x) * 8;
  if (base < 1392640u) {
    const float* src;
    if      (base < 1048576u) src = p0 + base;
    else if (base < 1310720u) src = p1 + (base - 1048576u);
    else if (base < 1376256u) src = p2 + (base - 1310720u);
    else                      src = p3 + (base - 1376256u);
    float4 lo = reinterpret_cast<const float4*>(src)[0];
    float4 hi = reinterpret_cast<const float4*>(src)[1];
    *reinterpret_cast<bf16x8*>(pb + base) = pack8(lo, hi);
  }
  if (blockIdx.x < (unsigned)nb) {
    int t = blockIdx.x * 256 + threadIdx.x;
    int lane = threadIdx.x & 63, w = threadIdx.x >> 6;
    int v = (t < n) ? inp[t] : -1;
    int b = (v < 0) ? -1 : bucket_of(v);
    __shared__ int cnt[4][4];
#pragma unroll
    for (int i = 0; i < 4; ++i) {
      unsigned long long m = __ballot(b == i);
      if (lane == 0) cnt[w][i] = __popcll(m);
    }
    __syncthreads();
    if (threadIdx.x < 4) {
      int s = cnt[0][threadIdx.x] + cnt[1][threadIdx.x] +
              cnt[2][threadIdx.x] + cnt[3][threadIdx.x];
      blkcnt[blockIdx.x * 4 + threadIdx.x] = s;
    }
  }
}

// ---------------------------------------------------------------------------
// Kernel 2: scatter with inline scan. Token-ascending lists. [r13/r15 verified]
// Entry packs (in-bucket row << 14) | token_id  (n = 16384 = 2^14).
// ---------------------------------------------------------------------------
__global__ __launch_bounds__(256) void scatter_kernel(const int* __restrict__ inp, int n,
                                                      const int* __restrict__ blkcnt, int nb,
                                                      unsigned* __restrict__ lists,
                                                      int* __restrict__ counts) {
  int t = blockIdx.x * 256 + threadIdx.x;
  int lane = threadIdx.x & 63, w = threadIdx.x >> 6;
  __shared__ int cnt[4][4];
  __shared__ int off_s[4];
  {
    int sv = (lane < nb) ? blkcnt[lane * 4 + w] : 0;
    int x = sv;
#pragma unroll
    for (int d = 1; d < 64; d <<= 1) {
      int y = __shfl_up(x, d);
      if (lane >= d) x += y;
    }
    int myoff = __shfl(x - sv, blockIdx.x);
    if (lane == 0) off_s[w] = myoff;
    if (blockIdx.x == 0 && lane == 63) counts[w] = x;
  }
  int v = (t < n) ? inp[t] : -1;
  int b = (v < 0) ? -1 : bucket_of(v);
  int lo = (b == 3) ? 200000 : (b == 2) ? 40000 : (b == 1) ? 20000 : 0;
  int myrank = 0;
#pragma unroll
  for (int i = 0; i < 4; ++i) {
    unsigned long long m = __ballot(b == i);
    if (lane == 0) cnt[w][i] = __popcll(m);
    if (b == i) myrank = __popcll(m & ((1ull << lane) - 1ull));
  }
  __syncthreads();
  if (b >= 0) {
    int prefix = 0;
    for (int w2 = 0; w2 < w; ++w2) prefix += cnt[w2][b];
    int pos = off_s[b] + prefix + myrank;
    lists[(size_t)b * n + pos] = ((unsigned)(v - lo) << 14) | (unsigned)t;
  }
}

// ---------------------------------------------------------------------------
// Heavy path: full-K (CHB chunks). Prefetch DISTANCE 2 (two static register
// sets, loop fully unrolled -> compile-time set indices). A gathered from
// fp32 emb (converted in staging); B direct bf16 from L2-resident pb (no
// conversion VALU, half bytes). LDS XOR swizzle byte ^= (row&7)<<4 (G4).
// [r15 verified correct]
// ---------------------------------------------------------------------------
template <int D, int CHB>
__device__ __forceinline__ void gemm_heavy(const float* __restrict__ emb,
                                           const unsigned short* __restrict__ pbD,
                                           const unsigned* __restrict__ list,
                                           int cnt, int r0, int c0,
                                           float* __restrict__ out, char* smem) {
  const int tid  = threadIdx.x;
  const int lane = tid & 63;
  const int w    = tid >> 6;
  const int wr   = w >> 1, wc = w & 1;     // 2x2 wave grid: 32 rows x 64 cols
  const int lr   = lane & 15, t16 = lane >> 4;

  char* Ab = smem;                          // A: 64 rows x 128 B  =  8 KB
  char* Bb = smem + 8192;                   // B: 128 cols x 128 B = 16 KB
  unsigned* toks = (unsigned*)(smem + 24576);

  if (tid < 64) {
    int p = r0 + tid;
    toks[tid] = (p < cnt) ? list[p] : 0u;   // pads -> row 0 (stores suppressed)
  }
  __syncthreads();

  int rowA[2], kkA[2], colB[4], kkB[4];
#pragma unroll
  for (int i = 0; i < 2; ++i) {
    int g = tid + i * 256;
    rowA[i] = g >> 3; kkA[i] = (g & 7) * 8;
  }
#pragma unroll
  for (int i = 0; i < 4; ++i) {
    int g = tid + i * 256;
    colB[i] = g >> 3; kkB[i] = (g & 7) * 8;
  }
  const float* abase[2];
#pragma unroll
  for (int i = 0; i < 2; ++i)
    abase[i] = emb + (size_t)(toks[rowA[i]] >> 14) * D + kkA[i];
  const unsigned short* bbase[4];
#pragma unroll
  for (int i = 0; i < 4; ++i)
    bbase[i] = pbD + (size_t)(c0 + colB[i]) * D + kkB[i];

  float4  arg[2][2][2];                     // [set][group][lo/hi]
  bf16x8  brg[2][4];                        // [set][group]

#define LOAD_SET(S_, K0_)                                                    \
  {                                                                          \
    _Pragma("unroll")                                                        \
    for (int i = 0; i < 2; ++i) {                                            \
      arg[S_][i][0] = *reinterpret_cast<const float4*>(abase[i] + (K0_));    \
      arg[S_][i][1] = *reinterpret_cast<const float4*>(abase[i] + (K0_) + 4);\
    }                                                                        \
    _Pragma("unroll")                                                        \
    for (int i = 0; i < 4; ++i)                                              \
      brg[S_][i] = *reinterpret_cast<const bf16x8*>(bbase[i] + (K0_));       \
  }

  LOAD_SET(0, 0)
  if (CHB > 1) LOAD_SET(1, 64)

  f32x4 acc[2][4];
#pragma unroll
  for (int fi = 0; fi < 2; ++fi)
#pragma unroll
    for (int fj = 0; fj < 4; ++fj) acc[fi][fj] = (f32x4){0.f, 0.f, 0.f, 0.f};

#pragma unroll
  for (int ch = 0; ch < CHB; ++ch) {
    const int cur = ch & 1;                 // compile-time after unroll
#pragma unroll
    for (int i = 0; i < 2; ++i) {
      bf16x8 o = pack8(arg[cur][i][0], arg[cur][i][1]);
      *reinterpret_cast<bf16x8*>(Ab + rowA[i] * 128 +
                                 ((kkA[i] * 2) ^ ((rowA[i] & 7) << 4))) = o;
    }
#pragma unroll
    for (int i = 0; i < 4; ++i)
      *reinterpret_cast<bf16x8*>(Bb + colB[i] * 128 +
                                 ((kkB[i] * 2) ^ ((colB[i] & 7) << 4))) = brg[cur][i];
    __syncthreads();

    if (ch + 2 < CHB) LOAD_SET(cur, (ch + 2) * 64)  // window ~1.5 chunks

#pragma unroll
    for (int s = 0; s < 2; ++s) {
      bf16x8 a[2], b[4];
#pragma unroll
      for (int fi = 0; fi < 2; ++fi) {
        int row = wr * 32 + fi * 16 + lr;
        a[fi] = *reinterpret_cast<const bf16x8*>(
            Ab + row * 128 + ((s * 64 + t16 * 16) ^ ((row & 7) << 4)));
      }
#pragma unroll
      for (int fj = 0; fj < 4; ++fj) {
        int col = wc * 64 + fj * 16 + lr;
        b[fj] = *reinterpret_cast<const bf16x8*>(
            Bb + col * 128 + ((s * 64 + t16 * 16) ^ ((col & 7) << 4)));
      }
#pragma unroll
      for (int fi = 0; fi < 2; ++fi)
#pragma unroll
        for (int fj = 0; fj < 4; ++fj)
          acc[fi][fj] = __builtin_amdgcn_mfma_f32_16x16x32_bf16(a[fi], b[fj], acc[fi][fj], 0, 0, 0);
    }
    __syncthreads();
  }
#undef LOAD_SET

  float* T = reinterpret_cast<float*>(smem + w * 4352);  // 16 rows x stride 68
#pragma unroll
  for (int fi = 0; fi < 2; ++fi) {
#pragma unroll
    for (int fj = 0; fj < 4; ++fj)
#pragma unroll
      for (int reg = 0; reg < 4; ++reg)
        T[(t16 * 4 + reg) * 68 + fj * 16 + lr] = acc[fi][fj][reg];
#pragma unroll
    for (int rr = 0; rr < 4; ++rr) {
      int p = wr * 32 + fi * 16 + rr * 4 + t16;
      if (r0 + p < cnt) {
        float4 v = *reinterpret_cast<const float4*>(&T[(rr * 4 + t16) * 68 + lr * 4]);
        *reinterpret_cast<float4*>(out + (size_t)(toks[p] & 16383u) * DPROJ +
                                   c0 + wc * 64 + lr * 4) = v;
      }
    }
  }
}

// ---------------------------------------------------------------------------
// Light path (D = 64 or 16): register-direct fragments; B from bf16 pb.
// [r15 verified correct]
// ---------------------------------------------------------------------------
template <int D>
__device__ __forceinline__ void gemm_light(const float* __restrict__ emb,
                                           const unsigned short* __restrict__ pbD,
                                           const unsigned* __restrict__ list,
                                           int cnt, int r0, int c0,
                                           float* __restrict__ out, char* smem) {
  constexpr int S = (D == 64) ? 2 : 1;
  const int tid  = threadIdx.x;
  const int lane = tid & 63;
  const int w    = tid >> 6;
  const int wr   = w >> 1, wc = w & 1;
  const int lr   = lane & 15, t16 = lane >> 4;

  unsigned* toks = (unsigned*)smem;
  if (tid < 64) {
    int p = r0 + tid;
    toks[tid] = (p < cnt) ? list[p] : 0u;
  }
  __syncthreads();

  bf16x8 a[2][S], b[4][S];
#pragma unroll
  for (int fi = 0; fi < 2; ++fi) {
    const float* eb = emb + (size_t)(toks[wr * 32 + fi * 16 + lr] >> 14) * D;
#pragma unroll
    for (int s = 0; s < S; ++s) {
      float4 lo = make_float4(0.f, 0.f, 0.f, 0.f), hi = lo;
      if (D == 64 || t16 < 2) {
        lo = *reinterpret_cast<const float4*>(eb + s * 32 + t16 * 8);
        hi = *reinterpret_cast<const float4*>(eb + s * 32 + t16 * 8 + 4);
      }
      a[fi][s] = pack8(lo, hi);
    }
  }
#pragma unroll
  for (int fj = 0; fj < 4; ++fj) {
    const unsigned short* pbc = pbD + (size_t)(c0 + wc * 64 + fj * 16 + lr) * D;
#pragma unroll
    for (int s = 0; s < S; ++s) {
      bf16x8 z = {0, 0, 0, 0, 0, 0, 0, 0};
      if (D == 64 || t16 < 2)
        z = *reinterpret_cast<const bf16x8*>(pbc + s * 32 + t16 * 8);
      b[fj][s] = z;
    }
  }

  f32x4 acc[2][4];
#pragma unroll
  for (int fi = 0; fi < 2; ++fi)
#pragma unroll
    for (int fj = 0; fj < 4; ++fj) acc[fi][fj] = (f32x4){0.f, 0.f, 0.f, 0.f};
#pragma unroll
  for (int s = 0; s < S; ++s)
#pragma unroll
    for (int fi = 0; fi < 2; ++fi)
#pragma unroll
      for (int fj = 0; fj < 4; ++fj)
        acc[fi][fj] = __builtin_amdgcn_mfma_f32_16x16x32_bf16(a[fi][s], b[fj][s], acc[fi][fj], 0, 0, 0);

  float* T = reinterpret_cast<float*>(smem + 256) + w * 1088;
#pragma unroll
  for (int fi = 0; fi < 2; ++fi) {
#pragma unroll
    for (int fj = 0; fj < 4; ++fj)
#pragma unroll
      for (int reg = 0; reg < 4; ++reg)
        T[(t16 * 4 + reg) * 68 + fj * 16 + lr] = acc[fi][fj][reg];
#pragma unroll
    for (int rr = 0; rr < 4; ++rr) {
      int p = wr * 32 + fi * 16 + rr * 4 + t16;
      if (r0 + p < cnt) {
        float4 v = *reinterpret_cast<const float4*>(&T[(rr * 4 + t16) * 68 + lr * 4]);
        *reinterpret_cast<float4*>(out + (size_t)(toks[p] & 16383u) * DPROJ +
                                   c0 + wc * 64 + lr * 4) = v;
      }
    }
  }
}

// ---------------------------------------------------------------------------
// Dispatcher: r12's XCD-grouping decode (best config). tile t = ((bx>>6)<<3)
// + (bx&7) -> the 8 col-slices of a tile have ids base+8c: same XCD, within
// a 64-id span. Heavy tiles first. Full-K b0 (no split-K).
// ---------------------------------------------------------------------------
__global__ __launch_bounds__(256) void gemm_all(
    const float* __restrict__ e0, const float* __restrict__ e1,
    const float* __restrict__ e2, const float* __restrict__ e3,
    const unsigned short* __restrict__ pb,
    const int* __restrict__ counts, const unsigned* __restrict__ lists,
    float* __restrict__ out, int n) {
  extern __shared__ char smem[];
  int bx = blockIdx.x;
  int t  = ((bx >> 6) << 3) + (bx & 7);
  int c0 = ((bx >> 3) & 7) * 128;
  int4 c = *reinterpret_cast<const int4*>(counts);
  int t0 = (c.x + 63) >> 6, t1 = (c.y + 63) >> 6,
      t2 = (c.z + 63) >> 6, t3 = (c.w + 63) >> 6;
  if (t < t0) { gemm_heavy<1024, 16>(e0, pb,           lists,               c.x, t * 64, c0, out, smem); return; }
  t -= t0;
  if (t < t1) { gemm_heavy< 256,  4>(e1, pb + 1048576, lists + (size_t)n,   c.y, t * 64, c0, out, smem); return; }
  t -= t1;
  if (t < t2) { gemm_light<64>(e2, pb + 1310720, lists + (size_t)2 * n, c.z, t * 64, c0, out, smem); return; }
  t -= t2;
  if (t < t3) { gemm_light<16>(e3, pb + 1376256, lists + (size_t)3 * n, c.w, t * 64, c0, out, smem); return; }
}

// ---------------------------------------------------------------------------
// Input order (setup_inputs dict order, verified rounds 1-15):
// inp, emb0, proj0, emb1, proj1, emb2, proj2, emb3, proj3.
// ws bytes: [0,16) counts | [16,1040) blkcnt | [1040,263184) lists |
// [524288, 3309568) pb bf16.
// ---------------------------------------------------------------------------
extern "C" void kernel_launch(void* const* d_in, const int* in_sizes, int n_in,
                              void* d_out, int out_size, void* d_ws, size_t ws_size,
                              hipStream_t stream) {
  const int*   inp   = (const int*)d_in[0];
  const float* emb0  = (const float*)d_in[1];
  const float* proj0 = (const float*)d_in[2];
  const float* emb1  = (const float*)d_in[3];
  const float* proj1 = (const float*)d_in[4];
  const float* emb2  = (const float*)d_in[5];
  const float* proj2 = (const float*)d_in[6];
  const float* emb3  = (const float*)d_in[7];
  const float* proj3 = (const float*)d_in[8];
  float* out = (float*)d_out;
  const int n = in_sizes[0];  // 16384 tokens

  int*            counts = (int*)d_ws;
  int*            blkcnt = (int*)d_ws + 4;
  unsigned*       lists  = (unsigned*)d_ws + 260;
  unsigned short* pb     = (unsigned short*)((char*)d_ws + 524288);

  const int nb = (n + 255) / 256;           // 64 (scan supports <= 64)
  convert_count<<<dim3(680), dim3(256), 0, stream>>>(proj0, proj1, proj2, proj3,
                                                     pb, inp, n, nb, blkcnt);
  scatter_kernel<<<dim3(nb), dim3(256), 0, stream>>>(inp, n, blkcnt, nb, lists, counts);

  // tiles: sum_i ceil(cnt_i/64) <= n/64 + 3 = 259; pad to 264 (multiple of 8).
  dim3 grid(264 * 8, 1, 1);
  size_t smem_bytes = 24576 + 64 * sizeof(unsigned);  // 24832 B -> 6 blocks/CU
  gemm_all<<<grid, dim3(256), smem_bytes, stream>>>(emb0, emb1, emb2, emb3, pb,
                                                    counts, lists, out, n);
}